// Round 1
// baseline (621.367 us; speedup 1.0000x reference)
//
#include <hip/hip_runtime.h>
#include <hip/hip_bf16.h>
#include <math.h>

// SimilarityTreeLSTM on MI355X — fp32 correctness-first baseline.
//
// Structure exploited: _build_children(512,4) is a deterministic complete
// 4-ary heap relabeled j = 511 - i, so depth levels form contiguous j-ranges:
//   depth5 [0,171) depth4 [171,427) depth3 [427,491)
//   depth2 [491,507) depth1 [507,511) depth0 [511,512)
// All nodes in a level are independent -> 6 batched phases instead of a
// 512-step scan. Both trees are batched together (rows: [left B | right B]).
// Pad child index == 512 is guarded to contribute 0 (matches reference's
// permanent zero row), so no state zero-init is required.

#define TM 64
#define TN 64
#define TK 16

__device__ __forceinline__ float sigm(float x) { return 1.0f / (1.0f + __expf(-x)); }

// ---------------- precompute GEMM: out[1024][N] = emb[tok[r]] @ W + bias ----
__global__ __launch_bounds__(256)
void gemm_pre(const float* __restrict__ emb,
              const int* __restrict__ ltok, const int* __restrict__ rtok,
              const float* __restrict__ W, const float* __restrict__ bias,
              float* __restrict__ out, int N)
{
    __shared__ float As[TK][TM + 4];
    __shared__ float Bs[TK][TN];
    const int tid = threadIdx.x;
    const int tileM = blockIdx.y * TM;
    const int tileN = blockIdx.x * TN;
    const int tx = tid & 15, ty = tid >> 4;

    const int am = tid >> 2;             // A row within tile (0..63)
    const int ak = (tid & 3) * 4;        // A k offset within K-tile
    const int arow = tileM + am;
    const int tok = (arow < 512) ? ltok[arow] : rtok[arow - 512];
    const float* Arow = emb + (size_t)tok * 512 + ak;

    const int bk = tid >> 4;             // 0..15
    const int bn = (tid & 15) * 4;       // 0..60

    float acc[4][4];
#pragma unroll
    for (int i = 0; i < 4; ++i)
#pragma unroll
        for (int j = 0; j < 4; ++j) acc[i][j] = 0.f;

    for (int k0 = 0; k0 < 512; k0 += TK) {
        float4 av = *(const float4*)(Arow + k0);
        As[ak + 0][am] = av.x; As[ak + 1][am] = av.y;
        As[ak + 2][am] = av.z; As[ak + 3][am] = av.w;
        float4 bv = *(const float4*)(W + (size_t)(k0 + bk) * N + tileN + bn);
        Bs[bk][bn + 0] = bv.x; Bs[bk][bn + 1] = bv.y;
        Bs[bk][bn + 2] = bv.z; Bs[bk][bn + 3] = bv.w;
        __syncthreads();
#pragma unroll
        for (int kk = 0; kk < TK; ++kk) {
            float a[4], b[4];
#pragma unroll
            for (int i = 0; i < 4; ++i) a[i] = As[kk][ty * 4 + i];
#pragma unroll
            for (int j = 0; j < 4; ++j) b[j] = Bs[kk][tx * 4 + j];
#pragma unroll
            for (int i = 0; i < 4; ++i)
#pragma unroll
                for (int j = 0; j < 4; ++j) acc[i][j] += a[i] * b[j];
        }
        __syncthreads();
    }
#pragma unroll
    for (int i = 0; i < 4; ++i) {
        const int r = tileM + ty * 4 + i;
        float* orow = out + (size_t)r * N + tileN;
#pragma unroll
        for (int j = 0; j < 4; ++j) {
            const int cn = tx * 4 + j;
            orow[cn] = acc[i][j] + bias[tileN + cn];
        }
    }
}

// ---------------- phase GEMM core (A direct, + bias + addmat epilogue) -----
__device__ __forceinline__
void gemm_core(const float* __restrict__ A, int M, int N,
               const float* __restrict__ W, const float* __restrict__ bias,
               const float* __restrict__ add, int addld,
               int lo, int B, int rdiv,
               float* __restrict__ out, int tileM, int tileN,
               float (*As)[TM + 4], float (*Bs)[TN])
{
    const int tid = threadIdx.x;
    const int tx = tid & 15, ty = tid >> 4;
    const int am = tid >> 2;
    const int ak = (tid & 3) * 4;
    const int arow = tileM + am;
    const bool aval = (arow < M);
    const float* Arow = A + (size_t)arow * 512 + ak;
    const int bk = tid >> 4;
    const int bn = (tid & 15) * 4;

    float acc[4][4];
#pragma unroll
    for (int i = 0; i < 4; ++i)
#pragma unroll
        for (int j = 0; j < 4; ++j) acc[i][j] = 0.f;

    for (int k0 = 0; k0 < 512; k0 += TK) {
        float4 av = aval ? *(const float4*)(Arow + k0) : make_float4(0.f, 0.f, 0.f, 0.f);
        As[ak + 0][am] = av.x; As[ak + 1][am] = av.y;
        As[ak + 2][am] = av.z; As[ak + 3][am] = av.w;
        float4 bv = *(const float4*)(W + (size_t)(k0 + bk) * N + tileN + bn);
        Bs[bk][bn + 0] = bv.x; Bs[bk][bn + 1] = bv.y;
        Bs[bk][bn + 2] = bv.z; Bs[bk][bn + 3] = bv.w;
        __syncthreads();
#pragma unroll
        for (int kk = 0; kk < TK; ++kk) {
            float a[4], b[4];
#pragma unroll
            for (int i = 0; i < 4; ++i) a[i] = As[kk][ty * 4 + i];
#pragma unroll
            for (int j = 0; j < 4; ++j) b[j] = Bs[kk][tx * 4 + j];
#pragma unroll
            for (int i = 0; i < 4; ++i)
#pragma unroll
                for (int j = 0; j < 4; ++j) acc[i][j] += a[i] * b[j];
        }
        __syncthreads();
    }
#pragma unroll
    for (int i = 0; i < 4; ++i) {
        const int r = tileM + ty * 4 + i;
        if (r >= M) continue;
        const int rr = r / rdiv;
        const int tree = (rr >= B) ? 1 : 0;
        const int jj = lo + rr - tree * B;
        const int addrow = tree * 512 + jj;
        const float* arow_add = add + (size_t)addrow * addld + tileN;
        float* orow = out + (size_t)r * N + tileN;
#pragma unroll
        for (int j = 0; j < 4; ++j) {
            const int cn = tx * 4 + j;
            orow[cn] = acc[i][j] + bias[tileN + cn] + arow_add[cn];
        }
    }
}

// One launch computes both per-level GEMMs (iou: [B2,512]x[512,1536],
// f: [4*B2,512]x[512,512]) via 1D tile decode.
__global__ __launch_bounds__(256)
void gemm_phase(const float* __restrict__ A1, int M1,
                const float* __restrict__ W1, const float* __restrict__ b1,
                const float* __restrict__ add1, float* __restrict__ out1,
                const float* __restrict__ A2, int M2,
                const float* __restrict__ W2, const float* __restrict__ b2,
                const float* __restrict__ add2, float* __restrict__ out2,
                int lo, int B, int ntile1, int mtiles1, int mtiles2)
{
    __shared__ float As[TK][TM + 4];
    __shared__ float Bs[TK][TN];
    int t = blockIdx.x;
    if (t < ntile1) {
        const int tm = t % mtiles1, tn = t / mtiles1;
        gemm_core(A1, M1, 1536, W1, b1, add1, 1536, lo, B, 1, out1, tm * TM, tn * TN, As, Bs);
    } else {
        t -= ntile1;
        const int tm = t % mtiles2, tn = t / mtiles2;
        gemm_core(A2, M2, 512, W2, b2, add2, 512, lo, B, 4, out2, tm * TM, tn * TN, As, Bs);
    }
}

// ---------------- per-level child gather: hsum + packed hh -----------------
__global__ void gather_phase(const float* __restrict__ h,
                             const int* __restrict__ lch, const int* __restrict__ rch,
                             float* __restrict__ hsum, float* __restrict__ hh,
                             int lo, int B)
{
    const int r = blockIdx.x;                  // 0..2B-1
    const int tree = (r >= B) ? 1 : 0;
    const int j = lo + r - tree * B;
    const int* ch = (tree ? rch : lch) + j * 4;
    const int c0 = ch[0], c1 = ch[1], c2 = ch[2], c3 = ch[3];
    const float* hb = h + (size_t)tree * 512 * 512;
    for (int col = threadIdx.x; col < 512; col += blockDim.x) {
        float v0 = (c0 < 512) ? hb[(size_t)c0 * 512 + col] : 0.f;
        float v1 = (c1 < 512) ? hb[(size_t)c1 * 512 + col] : 0.f;
        float v2 = (c2 < 512) ? hb[(size_t)c2 * 512 + col] : 0.f;
        float v3 = (c3 < 512) ? hb[(size_t)c3 * 512 + col] : 0.f;
        hh[((size_t)r * 4 + 0) * 512 + col] = v0;
        hh[((size_t)r * 4 + 1) * 512 + col] = v1;
        hh[((size_t)r * 4 + 2) * 512 + col] = v2;
        hh[((size_t)r * 4 + 3) * 512 + col] = v3;
        hsum[(size_t)r * 512 + col] = v0 + v1 + v2 + v3;
    }
}

// ---------------- per-level gating -----------------------------------------
__global__ void gating(const float* __restrict__ iou,
                       const float* __restrict__ fpre,
                       const int* __restrict__ lch, const int* __restrict__ rch,
                       float* __restrict__ h, float* __restrict__ c,
                       int lo, int B)
{
    const int r = blockIdx.x;                  // 0..2B-1
    const int tree = (r >= B) ? 1 : 0;
    const int j = lo + r - tree * B;
    const int* ch = (tree ? rch : lch) + j * 4;
    const int c0 = ch[0], c1 = ch[1], c2 = ch[2], c3 = ch[3];
    float* cb = c + (size_t)tree * 512 * 512;
    float* hb = h + (size_t)tree * 512 * 512;
    const float* iour = iou + (size_t)r * 1536;
    const float* fr = fpre + (size_t)r * 4 * 512;
    for (int col = threadIdx.x; col < 512; col += blockDim.x) {
        float ig = sigm(iour[col]);
        float og = sigm(iour[512 + col]);
        float ug = tanhf(iour[1024 + col]);
        float cv = ig * ug;
        if (c0 < 512) cv += sigm(fr[0 * 512 + col]) * cb[(size_t)c0 * 512 + col];
        if (c1 < 512) cv += sigm(fr[1 * 512 + col]) * cb[(size_t)c1 * 512 + col];
        if (c2 < 512) cv += sigm(fr[2 * 512 + col]) * cb[(size_t)c2 * 512 + col];
        if (c3 < 512) cv += sigm(fr[3 * 512 + col]) * cb[(size_t)c3 * 512 + col];
        cb[(size_t)j * 512 + col] = cv;
        hb[(size_t)j * 512 + col] = og * tanhf(cv);
    }
}

// ---------------- head ------------------------------------------------------
__global__ __launch_bounds__(256)
void head1(const float* __restrict__ c, const float* __restrict__ Wh,
           const float* __restrict__ bh, float* __restrict__ hid)
{
    __shared__ float vec[1024];
    __shared__ float red[256];
    const float* lc = c + (size_t)511 * 512;
    const float* rc = c + (size_t)(512 + 511) * 512;
    for (int k = threadIdx.x; k < 512; k += 256) {
        float a = lc[k], b = rc[k];
        vec[k] = a * b;
        vec[512 + k] = fabsf(a - b);
    }
    __syncthreads();
    const int lane = threadIdx.x & 63;
    const int ks = threadIdx.x >> 6;           // 0..3
    const int col = blockIdx.x * 64 + lane;
    float acc = 0.f;
    for (int k = ks; k < 1024; k += 4)
        acc += vec[k] * Wh[(size_t)k * 512 + col];
    red[threadIdx.x] = acc;
    __syncthreads();
    if (threadIdx.x < 64) {
        float s = red[lane] + red[64 + lane] + red[128 + lane] + red[192 + lane];
        hid[col] = sigm(s + bh[col]);
    }
}

__global__ void head2(const float* __restrict__ hid, const float* __restrict__ Wp,
                      const float* __restrict__ bp, float* __restrict__ out)
{
    const int lane = threadIdx.x;              // 64 threads, 1 wave
    float acc[5] = {0.f, 0.f, 0.f, 0.f, 0.f};
    for (int k = lane; k < 512; k += 64) {
        float hv = hid[k];
#pragma unroll
        for (int cc = 0; cc < 5; ++cc) acc[cc] += hv * Wp[k * 5 + cc];
    }
#pragma unroll
    for (int cc = 0; cc < 5; ++cc)
        for (int off = 32; off; off >>= 1) acc[cc] += __shfl_xor(acc[cc], off, 64);
    if (lane == 0) {
        float lg[5], m = -1e30f;
#pragma unroll
        for (int cc = 0; cc < 5; ++cc) { lg[cc] = acc[cc] + bp[cc]; m = fmaxf(m, lg[cc]); }
        float s = 0.f;
#pragma unroll
        for (int cc = 0; cc < 5; ++cc) s += __expf(lg[cc] - m);
        float lse = m + __logf(s);
#pragma unroll
        for (int cc = 0; cc < 5; ++cc) out[cc] = lg[cc] - lse;
    }
}

// ---------------- launch -----------------------------------------------------
extern "C" void kernel_launch(void* const* d_in, const int* in_sizes, int n_in,
                              void* d_out, int out_size, void* d_ws, size_t ws_size,
                              hipStream_t stream)
{
    const int*   lin     = (const int*)d_in[0];
    const int*   rin     = (const int*)d_in[1];
    const int*   lch     = (const int*)d_in[2];
    const int*   rch     = (const int*)d_in[3];
    const float* emb     = (const float*)d_in[4];
    const float* W_ioux  = (const float*)d_in[5];
    const float* b_ioux  = (const float*)d_in[6];
    const float* W_iouh  = (const float*)d_in[7];
    const float* b_iouh  = (const float*)d_in[8];
    const float* W_fx    = (const float*)d_in[9];
    const float* b_fx    = (const float*)d_in[10];
    const float* W_fh    = (const float*)d_in[11];
    const float* b_fh    = (const float*)d_in[12];
    const float* Wh      = (const float*)d_in[13];
    const float* bh      = (const float*)d_in[14];
    const float* Wp      = (const float*)d_in[15];
    const float* bp      = (const float*)d_in[16];
    float* out = (float*)d_out;

    float* ws   = (float*)d_ws;
    float* xiou = ws;                          // 1024*1536
    float* xf   = xiou + (size_t)1024 * 1536;  // 1024*512
    float* hbuf = xf   + (size_t)1024 * 512;   // 2*512*512
    float* cbuf = hbuf + (size_t)2 * 512 * 512;
    float* hsum = cbuf + (size_t)2 * 512 * 512; // 512*512
    float* hh   = hsum + (size_t)512 * 512;     // 2048*512
    float* ioub = hh   + (size_t)2048 * 512;    // 512*1536
    float* fpre = ioub + (size_t)512 * 1536;    // 2048*512
    float* hid  = fpre + (size_t)2048 * 512;    // 512
    (void)ws_size; (void)n_in; (void)in_sizes; (void)out_size;

    dim3 blk(256);

    // Hoisted input-side GEMMs: xiou = emb[tok]@W_ioux + b_ioux ; xf likewise.
    gemm_pre<<<dim3(1536 / TN, 1024 / TM), blk, 0, stream>>>(emb, lin, rin, W_ioux, b_ioux, xiou, 1536);
    gemm_pre<<<dim3(512 / TN, 1024 / TM), blk, 0, stream>>>(emb, lin, rin, W_fx, b_fx, xf, 512);

    static const int los[6] = {0, 171, 427, 491, 507, 511};
    static const int his[6] = {171, 427, 491, 507, 511, 512};
    for (int p = 0; p < 6; ++p) {
        const int lo = los[p], B = his[p] - los[p], B2 = 2 * B;
        gather_phase<<<B2, 256, 0, stream>>>(hbuf, lch, rch, hsum, hh, lo, B);
        const int mt1 = (B2 + TM - 1) / TM;
        const int mt2 = (4 * B2 + TM - 1) / TM;
        const int nt1 = mt1 * (1536 / TN);
        const int nt2 = mt2 * (512 / TN);
        gemm_phase<<<nt1 + nt2, blk, 0, stream>>>(hsum, B2, W_iouh, b_iouh, xiou, ioub,
                                                  hh, 4 * B2, W_fh, b_fh, xf, fpre,
                                                  lo, B, nt1, mt1, mt2);
        gating<<<B2, 256, 0, stream>>>(ioub, fpre, lch, rch, hbuf, cbuf, lo, B);
    }

    head1<<<8, 256, 0, stream>>>(cbuf, Wh, bh, hid);
    head2<<<1, 64, 0, stream>>>(hid, Wp, bp, out);
}

// Round 2
// 398.654 us; speedup vs baseline: 1.5587x; 1.5587x over previous
//
#include <hip/hip_runtime.h>
#include <hip/hip_bf16.h>
#include <math.h>

// SimilarityTreeLSTM on MI355X — round 2: bf16 MFMA GEMMs + fused gather +
// parallel head.
//
// Level decomposition (deterministic from _build_children(512,4), j = 511-i):
//   phase0 j[0,171) d5 | phase1 [171,427) d4 | phase2 [427,491) d3
//   phase3 [491,507) d2 | phase4 [507,511) d1 | phase5 [511,512) d0
// Children of a depth-d node are all at depth d+1 (the previous phase), so
// per-phase batching is exact. Pad child index 512 maps to a per-tree zero
// row: h/c state buffers are laid out [2][513][512] with row 512 of each tree
// zeroed once per call in prep (ws is re-poisoned 0xAA before every call).
//
// MFMA: v_mfma_f32_16x16x32_bf16. A-frag: lane holds A[m=lane&15][k=q*8+j],
// B-frag: B[k=q*8+j][n=lane&15] (we store W transposed so this is a 16B
// contiguous load), C/D: col=lane&15, row=q*4+reg.  [per guide §3, verified]

typedef __attribute__((ext_vector_type(8))) __bf16 bf16x8;
typedef __attribute__((ext_vector_type(4))) float f32x4;

__device__ __forceinline__ float sigm(float x) { return 1.0f / (1.0f + __expf(-x)); }

__device__ __forceinline__ unsigned short f2bf(float f) {
    union { float f; unsigned int u; } v; v.f = f;
    unsigned int r = v.u + 0x7FFF + ((v.u >> 16) & 1);
    return (unsigned short)(r >> 16);
}
__device__ __forceinline__ float bf2f(unsigned short b) {
    union { unsigned int u; float f; } v; v.u = ((unsigned int)b) << 16;
    return v.f;
}
__device__ __forceinline__ f32x4 mfma16(bf16x8 a, bf16x8 b, f32x4 c) {
    return __builtin_amdgcn_mfma_f32_16x16x32_bf16(a, b, c, 0, 0, 0);
}
__device__ __forceinline__ bf16x8 load_f32_as_bf8(const float* p) {
    float4 x = *(const float4*)p;
    float4 y = *(const float4*)(p + 4);
    bf16x8 r;
    r[0] = (__bf16)x.x; r[1] = (__bf16)x.y; r[2] = (__bf16)x.z; r[3] = (__bf16)x.w;
    r[4] = (__bf16)y.x; r[5] = (__bf16)y.y; r[6] = (__bf16)y.z; r[7] = (__bf16)y.w;
    return r;
}

// ---------------- prep: weight convert/transpose + zero rows ---------------
__device__ __forceinline__
void ttile(const float* __restrict__ src, int lds_, unsigned short* __restrict__ dst,
           int ldd, int k0, int n0, float (*ts)[33], int tid)
{
    const int tx = tid & 31, ty = tid >> 5;
#pragma unroll
    for (int i = 0; i < 4; ++i)
        ts[ty + 8 * i][tx] = src[(size_t)(k0 + ty + 8 * i) * lds_ + n0 + tx];
    __syncthreads();
#pragma unroll
    for (int i = 0; i < 4; ++i)
        dst[(size_t)(n0 + ty + 8 * i) * ldd + k0 + tx] = f2bf(ts[tx][ty + 8 * i]);
}

__global__ __launch_bounds__(256)
void prep(const float* __restrict__ W_iouh, const float* __restrict__ W_fh,
          const float* __restrict__ W_ioux, const float* __restrict__ W_fx,
          const float* __restrict__ Wh,
          unsigned short* __restrict__ WiouhT, unsigned short* __restrict__ WfhT,
          unsigned short* __restrict__ WxT, unsigned short* __restrict__ Whb,
          unsigned short* __restrict__ hbf, float* __restrict__ cbuf,
          float* __restrict__ hid_raw)
{
    __shared__ float ts[32][33];
    const int t = blockIdx.x, tid = threadIdx.x;
    if (t < 768) {                       // W_iouh [512][1536] -> WiouhT [1536][512]
        ttile(W_iouh, 1536, WiouhT, 512, (t & 15) * 32, (t >> 4) * 32, ts, tid);
    } else if (t < 1024) {               // W_fh -> WfhT
        const int tt = t - 768;
        ttile(W_fh, 512, WfhT, 512, (tt & 15) * 32, (tt >> 4) * 32, ts, tid);
    } else if (t < 1792) {               // W_ioux -> WxT rows [0,1536)
        const int tt = t - 1024;
        ttile(W_ioux, 1536, WxT, 512, (tt & 15) * 32, (tt >> 4) * 32, ts, tid);
    } else if (t < 2048) {               // W_fx -> WxT rows [1536,2048)
        const int tt = t - 1792;
        ttile(W_fx, 512, WxT + (size_t)1536 * 512, 512, (tt & 15) * 32, (tt >> 4) * 32, ts, tid);
    } else if (t < 2304) {               // Wh [1024][512] -> bf16 copy
        size_t base = (size_t)(t - 2048) * 2048 + tid;
#pragma unroll
        for (int i = 0; i < 8; ++i) Whb[base + 256 * i] = f2bf(Wh[base + 256 * i]);
    } else {                             // zero pad rows + hid accumulator
        for (int i = tid; i < 512; i += 256) {
            hbf[(size_t)512 * 512 + i] = 0;
            hbf[(size_t)1025 * 512 + i] = 0;
            cbuf[(size_t)512 * 512 + i] = 0.f;
            cbuf[(size_t)1025 * 512 + i] = 0.f;
            hid_raw[i] = 0.f;
        }
    }
}

// ---------------- pre-GEMM: xcat[1024][2048] = bf16(emb[tok]) @ WxT^T + b --
__global__ __launch_bounds__(256)
void prege(const float* __restrict__ emb, const int* __restrict__ lin,
           const int* __restrict__ rin, const unsigned short* __restrict__ WxT,
           const float* __restrict__ b_ioux, const float* __restrict__ b_fx,
           unsigned short* __restrict__ xcat)
{
    const int mt = blockIdx.x & 31, nb = blockIdx.x >> 5;
    const int tid = threadIdx.x, w = tid >> 6, lane = tid & 63;
    const int m = lane & 15, q = lane >> 4;
    const int colbase = nb * 256 + w * 64;
    const int r0 = mt * 32 + m, r1 = r0 + 16;
    const int tok0 = (r0 < 512) ? lin[r0] : rin[r0 - 512];
    const int tok1 = (r1 < 512) ? lin[r1] : rin[r1 - 512];
    const float* A0 = emb + (size_t)tok0 * 512;
    const float* A1 = emb + (size_t)tok1 * 512;

    f32x4 acc[2][4];
#pragma unroll
    for (int i = 0; i < 2; ++i)
#pragma unroll
        for (int j = 0; j < 4; ++j) acc[i][j] = (f32x4){0.f, 0.f, 0.f, 0.f};

    for (int k0 = 0; k0 < 512; k0 += 32) {
        const int koff = k0 + q * 8;
        bf16x8 a0 = load_f32_as_bf8(A0 + koff);
        bf16x8 a1 = load_f32_as_bf8(A1 + koff);
#pragma unroll
        for (int jj = 0; jj < 4; ++jj) {
            bf16x8 b = *(const bf16x8*)(WxT + (size_t)(colbase + jj * 16 + m) * 512 + koff);
            acc[0][jj] = mfma16(a0, b, acc[0][jj]);
            acc[1][jj] = mfma16(a1, b, acc[1][jj]);
        }
    }
#pragma unroll
    for (int i = 0; i < 2; ++i)
#pragma unroll
        for (int jj = 0; jj < 4; ++jj)
#pragma unroll
            for (int rr = 0; rr < 4; ++rr) {
                const int R = mt * 32 + i * 16 + q * 4 + rr;
                const int col = colbase + jj * 16 + m;
                const float bias = (col < 1536) ? b_ioux[col] : b_fx[col - 1536];
                xcat[(size_t)R * 2048 + col] = f2bf(acc[i][jj][rr] + bias);
            }
}

// ---------------- per-phase fused gather + dual GEMM -----------------------
__global__ __launch_bounds__(256)
void phase_gemm(const unsigned short* __restrict__ hbf,
                const int* __restrict__ lch, const int* __restrict__ rch,
                const unsigned short* __restrict__ WiouhT,
                const unsigned short* __restrict__ WfhT,
                const float* __restrict__ b_iouh, const float* __restrict__ b_fh,
                const unsigned short* __restrict__ xcat,
                float* __restrict__ ioub, float* __restrict__ fpre,
                int lo, int B, int nti1, int mti1, int mti2)
{
    const int B2 = 2 * B;
    const int tid = threadIdx.x, w = tid >> 6, lane = tid & 63;
    const int m = lane & 15, q = lane >> 4;
    int t = blockIdx.x;

    if (t < nti1) {
        // iou: [B2,512] (hsum, gathered on the fly) x [512,1536]
        const int mt = t % mti1, nb = t / mti1;
        const int colbase = nb * 256 + w * 64;
        const unsigned short* pA[2][4];
#pragma unroll
        for (int i = 0; i < 2; ++i) {
            const int r = mt * 32 + m + i * 16;
            int c[4] = {512, 512, 512, 512};
            int tree = 0;
            if (r < B2) {
                tree = (r >= B) ? 1 : 0;
                const int j = lo + r - tree * B;
                const int* ch = (tree ? rch : lch) + 4 * j;
                c[0] = ch[0]; c[1] = ch[1]; c[2] = ch[2]; c[3] = ch[3];
            }
            const unsigned short* hb = hbf + (size_t)tree * 513 * 512;
#pragma unroll
            for (int s = 0; s < 4; ++s) pA[i][s] = hb + (size_t)c[s] * 512;
        }
        f32x4 acc[2][4];
#pragma unroll
        for (int i = 0; i < 2; ++i)
#pragma unroll
            for (int j = 0; j < 4; ++j) acc[i][j] = (f32x4){0.f, 0.f, 0.f, 0.f};

        for (int k0 = 0; k0 < 512; k0 += 32) {
            const int koff = k0 + q * 8;
            bf16x8 af[2];
#pragma unroll
            for (int i = 0; i < 2; ++i) {
                float s[8] = {0.f, 0.f, 0.f, 0.f, 0.f, 0.f, 0.f, 0.f};
#pragma unroll
                for (int cc = 0; cc < 4; ++cc) {
                    bf16x8 v = *(const bf16x8*)(pA[i][cc] + koff);
#pragma unroll
                    for (int j = 0; j < 8; ++j) s[j] += (float)v[j];
                }
                bf16x8 a;
#pragma unroll
                for (int j = 0; j < 8; ++j) a[j] = (__bf16)s[j];
                af[i] = a;
            }
#pragma unroll
            for (int jj = 0; jj < 4; ++jj) {
                bf16x8 b = *(const bf16x8*)(WiouhT + (size_t)(colbase + jj * 16 + m) * 512 + koff);
                acc[0][jj] = mfma16(af[0], b, acc[0][jj]);
                acc[1][jj] = mfma16(af[1], b, acc[1][jj]);
            }
        }
#pragma unroll
        for (int i = 0; i < 2; ++i)
#pragma unroll
            for (int jj = 0; jj < 4; ++jj)
#pragma unroll
                for (int rr = 0; rr < 4; ++rr) {
                    const int R = mt * 32 + i * 16 + q * 4 + rr;
                    if (R < B2) {
                        const int tr = (R >= B) ? 1 : 0;
                        const int jR = lo + R - tr * B;
                        const int col = colbase + jj * 16 + m;
                        ioub[(size_t)R * 1536 + col] = acc[i][jj][rr] + b_iouh[col]
                            + bf2f(xcat[(size_t)(tr * 512 + jR) * 2048 + col]);
                    }
                }
    } else {
        // f: [4*B2,512] (child h rows, direct) x [512,512]
        t -= nti1;
        const int mt = t % mti2, nb = t / mti2;
        const int colbase = nb * 256 + w * 64;
        const unsigned short* pA[2];
#pragma unroll
        for (int i = 0; i < 2; ++i) {
            const int rf = mt * 32 + m + i * 16;
            int tree = 0, c = 512;
            if (rf < 4 * B2) {
                const int r = rf >> 2, s = rf & 3;
                tree = (r >= B) ? 1 : 0;
                const int j = lo + r - tree * B;
                c = ((tree ? rch : lch) + 4 * j)[s];
            }
            pA[i] = hbf + ((size_t)tree * 513 + c) * 512;
        }
        f32x4 acc[2][4];
#pragma unroll
        for (int i = 0; i < 2; ++i)
#pragma unroll
            for (int j = 0; j < 4; ++j) acc[i][j] = (f32x4){0.f, 0.f, 0.f, 0.f};

        for (int k0 = 0; k0 < 512; k0 += 32) {
            const int koff = k0 + q * 8;
            bf16x8 a0 = *(const bf16x8*)(pA[0] + koff);
            bf16x8 a1 = *(const bf16x8*)(pA[1] + koff);
#pragma unroll
            for (int jj = 0; jj < 4; ++jj) {
                bf16x8 b = *(const bf16x8*)(WfhT + (size_t)(colbase + jj * 16 + m) * 512 + koff);
                acc[0][jj] = mfma16(a0, b, acc[0][jj]);
                acc[1][jj] = mfma16(a1, b, acc[1][jj]);
            }
        }
#pragma unroll
        for (int i = 0; i < 2; ++i)
#pragma unroll
            for (int jj = 0; jj < 4; ++jj)
#pragma unroll
                for (int rr = 0; rr < 4; ++rr) {
                    const int R = mt * 32 + i * 16 + q * 4 + rr;
                    if (R < 4 * B2) {
                        const int rR = R >> 2;
                        const int tr = (rR >= B) ? 1 : 0;
                        const int jR = lo + rR - tr * B;
                        const int col = colbase + jj * 16 + m;
                        fpre[(size_t)R * 512 + col] = acc[i][jj][rr] + b_fh[col]
                            + bf2f(xcat[(size_t)(tr * 512 + jR) * 2048 + 1536 + col]);
                    }
                }
    }
}

// ---------------- per-level gating (writes c fp32, h bf16) -----------------
__global__ __launch_bounds__(256)
void gating_k(const float* __restrict__ ioub, const float* __restrict__ fpre,
              const int* __restrict__ lch, const int* __restrict__ rch,
              float* __restrict__ cbuf, unsigned short* __restrict__ hbf,
              int lo, int B)
{
    const int r = blockIdx.x;
    const int tree = (r >= B) ? 1 : 0;
    const int j = lo + r - tree * B;
    const int* ch = (tree ? rch : lch) + 4 * j;
    const int c0 = ch[0], c1 = ch[1], c2 = ch[2], c3 = ch[3];
    float* cb = cbuf + (size_t)tree * 513 * 512;
    unsigned short* hb = hbf + (size_t)tree * 513 * 512;
    const float* ir = ioub + (size_t)r * 1536;
    const float* fr = fpre + (size_t)r * 4 * 512;
#pragma unroll
    for (int u = 0; u < 2; ++u) {
        const int col = threadIdx.x + u * 256;
        const float ig = sigm(ir[col]);
        const float og = sigm(ir[512 + col]);
        const float ug = tanhf(ir[1024 + col]);
        float cv = ig * ug
            + sigm(fr[col])        * cb[(size_t)c0 * 512 + col]
            + sigm(fr[512 + col])  * cb[(size_t)c1 * 512 + col]
            + sigm(fr[1024 + col]) * cb[(size_t)c2 * 512 + col]
            + sigm(fr[1536 + col]) * cb[(size_t)c3 * 512 + col];
        cb[(size_t)j * 512 + col] = cv;
        hb[(size_t)j * 512 + col] = f2bf(og * tanhf(cv));
    }
}

// ---------------- head -----------------------------------------------------
__global__ __launch_bounds__(256)
void head1(const float* __restrict__ cbuf, const unsigned short* __restrict__ Whb,
           float* __restrict__ hid_raw)
{
    __shared__ float red[4][64];
    const float* lc = cbuf + (size_t)511 * 512;
    const float* rc = cbuf + (size_t)(513 + 511) * 512;
    const int tid = threadIdx.x, w = tid >> 6, lane = tid & 63;
    const int cg = blockIdx.x & 7, kg = blockIdx.x >> 3;
    const int col = cg * 64 + lane;
    const int kbase = kg * 128 + w * 32;
    float acc = 0.f;
#pragma unroll 8
    for (int i = 0; i < 32; ++i) {
        const int k = kbase + i;
        float v;
        if (k < 512) v = lc[k] * rc[k];
        else { const int kk = k - 512; v = fabsf(lc[kk] - rc[kk]); }
        acc += v * bf2f(Whb[(size_t)k * 512 + col]);
    }
    red[w][lane] = acc;
    __syncthreads();
    if (w == 0)
        atomicAdd(&hid_raw[col], red[0][lane] + red[1][lane] + red[2][lane] + red[3][lane]);
}

__global__ __launch_bounds__(256)
void head2(const float* __restrict__ hid_raw, const float* __restrict__ bh,
           const float* __restrict__ Wp, const float* __restrict__ bp,
           float* __restrict__ out)
{
    __shared__ float red[4][5];
    const int tid = threadIdx.x, w = tid >> 6, lane = tid & 63;
    float a[5] = {0.f, 0.f, 0.f, 0.f, 0.f};
    for (int k = tid; k < 512; k += 256) {
        const float hv = sigm(hid_raw[k] + bh[k]);
#pragma unroll
        for (int cc = 0; cc < 5; ++cc) a[cc] += hv * Wp[(size_t)k * 5 + cc];
    }
#pragma unroll
    for (int cc = 0; cc < 5; ++cc)
        for (int off = 32; off; off >>= 1) a[cc] += __shfl_xor(a[cc], off, 64);
    if (lane == 0)
#pragma unroll
        for (int cc = 0; cc < 5; ++cc) red[w][cc] = a[cc];
    __syncthreads();
    if (tid == 0) {
        float lg[5], mx = -1e30f;
#pragma unroll
        for (int cc = 0; cc < 5; ++cc) {
            lg[cc] = red[0][cc] + red[1][cc] + red[2][cc] + red[3][cc] + bp[cc];
            mx = fmaxf(mx, lg[cc]);
        }
        float s = 0.f;
#pragma unroll
        for (int cc = 0; cc < 5; ++cc) s += __expf(lg[cc] - mx);
        const float lse = mx + __logf(s);
#pragma unroll
        for (int cc = 0; cc < 5; ++cc) out[cc] = lg[cc] - lse;
    }
}

// ---------------- launch ----------------------------------------------------
extern "C" void kernel_launch(void* const* d_in, const int* in_sizes, int n_in,
                              void* d_out, int out_size, void* d_ws, size_t ws_size,
                              hipStream_t stream)
{
    const int*   lin     = (const int*)d_in[0];
    const int*   rin     = (const int*)d_in[1];
    const int*   lch     = (const int*)d_in[2];
    const int*   rch     = (const int*)d_in[3];
    const float* emb     = (const float*)d_in[4];
    const float* W_ioux  = (const float*)d_in[5];
    const float* b_ioux  = (const float*)d_in[6];
    const float* W_iouh  = (const float*)d_in[7];
    const float* b_iouh  = (const float*)d_in[8];
    const float* W_fx    = (const float*)d_in[9];
    const float* b_fx    = (const float*)d_in[10];
    const float* W_fh    = (const float*)d_in[11];
    const float* b_fh    = (const float*)d_in[12];
    const float* Wh      = (const float*)d_in[13];
    const float* bh      = (const float*)d_in[14];
    const float* Wp      = (const float*)d_in[15];
    const float* bp      = (const float*)d_in[16];
    float* out = (float*)d_out;
    (void)ws_size; (void)n_in; (void)in_sizes; (void)out_size;

    char* p = (char*)d_ws;
    unsigned short* WiouhT = (unsigned short*)p;            p += (size_t)1536 * 512 * 2;
    unsigned short* WfhT   = (unsigned short*)p;            p += (size_t)512 * 512 * 2;
    unsigned short* WxT    = (unsigned short*)p;            p += (size_t)2048 * 512 * 2;
    unsigned short* Whb    = (unsigned short*)p;            p += (size_t)1024 * 512 * 2;
    unsigned short* xcat   = (unsigned short*)p;            p += (size_t)1024 * 2048 * 2;
    unsigned short* hbf    = (unsigned short*)p;            p += (size_t)2 * 513 * 512 * 2;
    float*          cbuf   = (float*)p;                     p += (size_t)2 * 513 * 512 * 4;
    float*          ioub   = (float*)p;                     p += (size_t)512 * 1536 * 4;
    float*          fpre   = (float*)p;                     p += (size_t)2048 * 512 * 4;
    float*          hid_raw= (float*)p;                     p += (size_t)512 * 4;

    prep<<<2305, 256, 0, stream>>>(W_iouh, W_fh, W_ioux, W_fx, Wh,
                                   WiouhT, WfhT, WxT, Whb, hbf, cbuf, hid_raw);
    prege<<<256, 256, 0, stream>>>(emb, lin, rin, WxT, b_ioux, b_fx, xcat);

    static const int los[6] = {0, 171, 427, 491, 507, 511};
    static const int his[6] = {171, 427, 491, 507, 511, 512};
    for (int ph = 0; ph < 6; ++ph) {
        const int lo = los[ph], B = his[ph] - los[ph], B2 = 2 * B;
        const int mti1 = (B2 + 31) / 32;
        const int mti2 = (4 * B2 + 31) / 32;
        const int nti1 = mti1 * 6;          // 1536 / 256
        const int nti2 = mti2 * 2;          // 512 / 256
        phase_gemm<<<nti1 + nti2, 256, 0, stream>>>(hbf, lch, rch, WiouhT, WfhT,
                                                    b_iouh, b_fh, xcat, ioub, fpre,
                                                    lo, B, nti1, mti1, mti2);
        gating_k<<<B2, 256, 0, stream>>>(ioub, fpre, lch, rch, cbuf, hbf, lo, B);
    }

    head1<<<64, 256, 0, stream>>>(cbuf, Whb, hid_raw);
    head2<<<1, 256, 0, stream>>>(hid_raw, bh, Wp, bp, out);
}